// Round 7
// baseline (252.070 us; speedup 1.0000x reference)
//
#include <hip/hip_runtime.h>

#define LOG2E 1.44269504088896340736f
#define LN2   0.69314718055994530942f

typedef short bf8 __attribute__((ext_vector_type(8)));   // 8 bf16 (A/B frag)
typedef float f4  __attribute__((ext_vector_type(4)));   // 4 f32  (C/D frag)
typedef float v2f __attribute__((ext_vector_type(2)));   // packed f32 pair

static __device__ __forceinline__ unsigned short f2bf_rne(float f) {
    unsigned u = __float_as_uint(f);
    u += 0x7FFFu + ((u >> 16) & 1u);
    return (unsigned short)(u >> 16);
}
// pack two f32 -> two bf16 (truncation; verified absmax 0.0 in R6)
static __device__ __forceinline__ unsigned pack_bf_trunc(float lo, float hi) {
    return __builtin_amdgcn_perm(__float_as_uint(hi), __float_as_uint(lo), 0x07060302u);
}

// ============================================================================
// Kernel 1: per-(batch, 64-step chunk) operator product.
//   Op_t = mask_t ? D_t * M^T : I,  D_t = diag(exp(em_t) * 2^-7), M = exp(tr)
//   P_c  = Op_{t0+63} ... Op_{t0}   (64x64), stored bf16 to workspace as P^T.
// One wave per chunk; 4096 blocks (16 waves/CU). Throughput-bound: the step
// body is tuned for VALU issue count (hoisted zero C-operand, packed f32
// muls, b128 d-reads). LDS layout STR=72 is phase-optimal for both the
// b128 B-frag reads and b64 C-writes (bank arithmetic, R6 post-mortem).
// ============================================================================
__global__ __attribute__((amdgpu_flat_work_group_size(64, 64), amdgpu_waves_per_eu(1, 4)))
void crf_scan(const int* __restrict__ yg, const float* __restrict__ em,
              const float* __restrict__ tr, unsigned short* __restrict__ Pg)
{
    constexpr int T = 1024, STR = 72;
    const int c = blockIdx.x, b = blockIdx.y;
    const int lane = threadIdx.x, nl = lane & 15, q = lane >> 4;

    __shared__ __align__(16) unsigned short p_sh[64 * STR];  // P^T: p_sh[n*STR+k] = P[k][n]
    __shared__ __align__(16) float d_sh[64];

    // ---- P = I (single wave => DS pipe in-order; no barriers needed) ----
    #pragma unroll
    for (int r = 0; r < 9; ++r) {
        uint4 z; z.x = z.y = z.z = z.w = 0u;
        *(uint4*)&p_sh[lane * STR + r * 8] = z;
    }
    p_sh[lane * STR + lane] = 0x3F80;   // bf16 1.0

    // ---- A-fragments of M^T (constant): A[m][k]=exp(tr[k][m]) ----
    bf8 afr[4][2];
    #pragma unroll
    for (int mt = 0; mt < 4; ++mt)
        #pragma unroll
        for (int kt = 0; kt < 2; ++kt) {
            bf8 v;
            #pragma unroll
            for (int j = 0; j < 8; ++j) {
                const int k = 32 * kt + 8 * q + j, m = 16 * mt + nl;
                v[j] = (short)f2bf_rne(exp2f(tr[k * 64 + m] * LOG2E));
            }
            afr[mt][kt] = v;
        }

    const int t0 = 1 + 64 * c;
    const int nsteps = (c == 15) ? 63 : 64;
    const float* emb = em + (size_t)b * T * 64;

    int tl = t0 + lane; if (tl > T - 1) tl = T - 1;
    const int yvl = yg[b * T + tl];
    const unsigned long long msk = __ballot(lane < nsteps && yvl != 0);

    const f4 zf4 = {0.f, 0.f, 0.f, 0.f};   // loop-invariant MFMA C-operand

    float ldc = emb[t0 * 64 + lane];        // emission prefetch (1 deep)
    for (int s = 0; s < nsteps; ++s) {
        int tn = t0 + s + 1; if (tn > T - 1) tn = T - 1;
        const float ldn = emb[tn * 64 + lane];
        if ((msk >> s) & 1ull) {            // wave-uniform
            d_sh[lane] = exp2f(ldc * LOG2E - 7.0f);   // d[state=lane]
            // B-fragments of current P: B[k][n], n=lane&15, k=8*(lane>>4)+j
            bf8 bfr[2][4];
            #pragma unroll
            for (int kt = 0; kt < 2; ++kt)
                #pragma unroll
                for (int nt = 0; nt < 4; ++nt)
                    bfr[kt][nt] = *(const bf8*)&p_sh[(16 * nt + nl) * STR + 32 * kt + 8 * q];
            // d for my C rows: rows 16*mt+4*q+0..3 -> one b128 per mt
            v2f d01[4], d23[4];
            #pragma unroll
            for (int mt = 0; mt < 4; ++mt) {
                const f4 dv = *(const f4*)&d_sh[16 * mt + 4 * q];
                d01[mt] = (v2f){dv[0], dv[1]};
                d23[mt] = (v2f){dv[2], dv[3]};
            }
            // C = M^T * P (f32); row-scale via packed muls; truncate->bf16
            #pragma unroll
            for (int mt = 0; mt < 4; ++mt)
                #pragma unroll
                for (int nt = 0; nt < 4; ++nt) {
                    f4 acc = __builtin_amdgcn_mfma_f32_16x16x32_bf16(
                                 afr[mt][0], bfr[0][nt], zf4, 0, 0, 0);
                    acc = __builtin_amdgcn_mfma_f32_16x16x32_bf16(
                                 afr[mt][1], bfr[1][nt], acc, 0, 0, 0);
                    const v2f lo = (v2f){acc[0], acc[1]} * d01[mt];   // v_pk_mul_f32
                    const v2f hi = (v2f){acc[2], acc[3]} * d23[mt];
                    uint2 w;
                    w.x = pack_bf_trunc(lo.x, lo.y);
                    w.y = pack_bf_trunc(hi.x, hi.y);
                    *(uint2*)&p_sh[(16 * nt + nl) * STR + 16 * mt + 4 * q] = w;
                }
        }
        ldc = ldn;
    }

    // ---- dump P^T rows: Pg[(b*16+c)*4096 + n*64 + k] = P_c[k][n] ----
    unsigned short* pg = Pg + ((size_t)(b * 16 + c) << 12);
    #pragma unroll
    for (int r = 0; r < 8; ++r)
        *(uint4*)(pg + lane * 64 + r * 8) = *(const uint4*)&p_sh[lane * STR + r * 8];
}

// ============================================================================
// Kernel 2: per-batch combine — v = P_15 ... P_0 * exp(e0 - M0), plus gather
// scores, logZ, final -mean. 256 waves; chunk rows double-buffered in regs.
// ============================================================================
__global__ __attribute__((amdgpu_flat_work_group_size(64, 64), amdgpu_waves_per_eu(1, 1)))
void crf_combine(const int* __restrict__ yg, const float* __restrict__ em,
                 const float* __restrict__ tr, const unsigned short* __restrict__ Pg,
                 float* __restrict__ out)
{
    constexpr int T = 1024;
    const int b = blockIdx.x, j = threadIdx.x;
    __shared__ __align__(16) float v_sh[64];

    const float e0 = em[(size_t)b * T * 64 + j];
    float M0 = e0;
    #pragma unroll
    for (int o = 32; o > 0; o >>= 1) M0 = fmaxf(M0, __shfl_xor(M0, o, 64));
    float v = exp2f((e0 - M0) * LOG2E);
    float L = M0;

    // ---- scores + unmasked-step count (lane-strided over t) ----
    const int* yb = yg + b * T;
    int cnt = 0; float ep = 0.f, tp = 0.f;
    for (int t = 1 + j; t < T; t += 64) {
        const int yt = yb[t];
        if (yt != 0) {
            ++cnt;
            tp += tr[yb[t - 1] * 64 + yt];
            ep += em[((size_t)b * T + t) * 64 + yt];
        }
    }
    if (j == 0) {
        const int y0 = yb[0];
        if (y0 != 0) ep += em[(size_t)b * T * 64 + y0];
    }

    // ---- apply the 16 chunk operators (rows double-buffered in registers) ----
    const unsigned short* pgb = Pg + ((size_t)(b * 16) << 12) + j * 64;
    uint4 r0, r1, r2, r3, r4, r5, r6, r7;
    {
        const uint4* p = (const uint4*)pgb;
        r0 = p[0]; r1 = p[1]; r2 = p[2]; r3 = p[3];
        r4 = p[4]; r5 = p[5]; r6 = p[6]; r7 = p[7];
    }
    for (int c = 0; c < 16; ++c) {
        uint4 n0, n1, n2, n3, n4, n5, n6, n7;
        if (c < 15) {
            const uint4* p = (const uint4*)(pgb + ((size_t)(c + 1) << 12));
            n0 = p[0]; n1 = p[1]; n2 = p[2]; n3 = p[3];
            n4 = p[4]; n5 = p[5]; n6 = p[6]; n7 = p[7];
        }
        v_sh[j] = v;                       // single wave: in-order DS pipe
        float s0 = 0.f, s1 = 0.f, s2 = 0.f, s3 = 0.f;
        const uint4 qs[8] = {r0, r1, r2, r3, r4, r5, r6, r7};
        #pragma unroll
        for (int r = 0; r < 8; ++r) {
            const uint4 qq = qs[r];
            const float* vp = &v_sh[r * 8];
            s0 = fmaf(__uint_as_float(qq.x << 16),         vp[0], s0);
            s1 = fmaf(__uint_as_float(qq.x & 0xFFFF0000u), vp[1], s1);
            s2 = fmaf(__uint_as_float(qq.y << 16),         vp[2], s2);
            s3 = fmaf(__uint_as_float(qq.y & 0xFFFF0000u), vp[3], s3);
            s0 = fmaf(__uint_as_float(qq.z << 16),         vp[4], s0);
            s1 = fmaf(__uint_as_float(qq.z & 0xFFFF0000u), vp[5], s1);
            s2 = fmaf(__uint_as_float(qq.w << 16),         vp[6], s2);
            s3 = fmaf(__uint_as_float(qq.w & 0xFFFF0000u), vp[7], s3);
        }
        float s = (s0 + s1) + (s2 + s3);
        // exact-pow2 re-centering (wave-uniform), fold into L
        const unsigned sb = (unsigned)__builtin_amdgcn_readlane((int)__float_as_uint(s), 0);
        const int ef = (int)((sb >> 23) & 0xFF);
        if (ef > 0 && ef < 255 && ef != 127) {
            const int E = ef - 127;
            s *= __uint_as_float((unsigned)(127 - E) << 23);
            L += (float)E * LN2;
        }
        v = s;
        if (c < 15) {
            r0 = n0; r1 = n1; r2 = n2; r3 = n3;
            r4 = n4; r5 = n5; r6 = n6; r7 = n7;
        }
    }

    // ---- reduce & finalize ----
    float vs = v, eps = ep, tps = tp; int cs = cnt;
    #pragma unroll
    for (int o = 32; o > 0; o >>= 1) {
        vs  += __shfl_xor(vs, o, 64);
        eps += __shfl_xor(eps, o, 64);
        tps += __shfl_xor(tps, o, 64);
        cs  += __shfl_xor(cs, o, 64);
    }
    if (j == 0) {
        const float logz = L + 7.0f * LN2 * (float)cs + __log2f(vs) * LN2;
        const float ll = eps + tps - logz;
        atomicAdd(out, ll * (-1.0f / 256.0f));
    }
}

extern "C" void kernel_launch(void* const* d_in, const int* in_sizes, int n_in,
                              void* d_out, int out_size, void* d_ws, size_t ws_size,
                              hipStream_t stream) {
    const int*   y  = (const int*)d_in[0];
    const float* em = (const float*)d_in[1];
    const float* tr = (const float*)d_in[2];
    float* out = (float*)d_out;
    unsigned short* Pg = (unsigned short*)d_ws;   // 256*16*4096*2 = 32 MB

    hipMemsetAsync(out, 0, sizeof(float), stream);
    crf_scan<<<dim3(16, 256), dim3(64), 0, stream>>>(y, em, tr, Pg);
    crf_combine<<<dim3(256), dim3(64), 0, stream>>>(y, em, tr, Pg, out);
}